// Round 1
// baseline (273.842 us; speedup 1.0000x reference)
//
#include <hip/hip_runtime.h>
#include <math.h>

#define NB 16
#define NN 24
#define NA 384       /* atoms total */
#define FF 128
#define CC 27
#define MAXNBR 32    /* physically <= 23 possible (image spacing L > 2r) */

// ---- static device scratch (d_ws unused). Counters are zero at load and reset by
// the unique finisher blocks each call -> clean state per graph replay.
__device__ float g_sigma[4];
__device__ float g_projA[NA*4*FF];  // P0, then P2
__device__ float g_projB[NA*4*FF];  // P1
__device__ float g_feat [NA*FF];    // final feats (agent-scope)
__device__ int   g_cnt4 [4*NB];     // per-layer per-batch arrival counters
__device__ int   g_sigdone;         // sigma blocks done (0..3)
__device__ int   g_batchdone;       // finished batches (0..NB)

__device__ __forceinline__ float softplusf(float x){ return fmaxf(x,0.f) + log1pf(expf(-fabsf(x))); }
__device__ __forceinline__ float sigmoidf(float x){ return 1.f/(1.f+expf(-x)); }
__device__ __forceinline__ void st_agent(float* p, float v){
  __hip_atomic_store(p, v, __ATOMIC_RELAXED, __HIP_MEMORY_SCOPE_AGENT);
}
__device__ __forceinline__ float ld_agent(const float* p){
  return __hip_atomic_load(p, __ATOMIC_RELAXED, __HIP_MEMORY_SCOPE_AGENT);
}

// Fixed-trip banded Gaussian dot: 20 fully-unrolled terms covering the +-9*step band.
// Terms outside the true band have gauss < 2e-18 -> invisible in fp32 sums.
__device__ __forceinline__ void band_dot(float dist, const float* __restrict__ Wf2,
                                         const float* __restrict__ Ws2, int f,
                                         float& ge, float& se)
{
  const float step  = 6.0f/127.0f;
  const float coeff = -0.5f/(step*step);
  int kmin = (int)ceilf(dist/step - 9.0f);
  kmin = kmin < 0 ? 0 : (kmin > 108 ? 108 : kmin);
  float g = 0.f, s = 0.f;
  #pragma unroll
  for (int t = 0; t < 20; t++) {
    int k = kmin + t;
    float dd = dist - step*(float)k;
    float a  = expf(coeff*dd*dd);
    g += a * Wf2[k*FF+f];
    s += a * Ws2[k*FF+f];
  }
  ge = g; se = s;
}

// per-quarter GEMV: quarter q computes one of {gi,gj,si,sj} columns
__device__ __forceinline__ float gemv_q(const float* __restrict__ Wf,
                                        const float* __restrict__ Ws,
                                        const float* s_ft, int q, int f)
{
  const float* W = (q==0) ? Wf : (q==1) ? (Wf + FF*FF) : (q==2) ? Ws : (Ws + FF*FF);
  float s = 0.f;
  #pragma unroll 16
  for (int k = 0; k < FF; k++) s += s_ft[k]*W[k*FF+f];
  return s;
}

// publish own stores at LLC, then bump the per-batch arrival counter
__device__ __forceinline__ void publish(int* ctr)
{
  asm volatile("s_waitcnt vmcnt(0)" ::: "memory");   // own agent stores at LLC
  __syncthreads();                                    // whole block drained
  if (threadIdx.x == 0)
    __hip_atomic_fetch_add(ctr, 1, __ATOMIC_RELEASE, __HIP_MEMORY_SCOPE_AGENT);
}

// spin (tid 0 only, bounded) until counter reaches target, then block-wide barrier
__device__ __forceinline__ void wait_ge(int* ctr, int target)
{
  if (threadIdx.x == 0) {
    int guard = 0;
    while (__hip_atomic_load(ctr, __ATOMIC_ACQUIRE, __HIP_MEMORY_SCOPE_AGENT) < target) {
      __builtin_amdgcn_s_sleep(2);
      if (++guard > (1<<20)) break;   // fail visibly (absmax) instead of hanging
    }
  }
  __syncthreads();
}

// edge phase of layer l: msg accumulate + residual softplus update of s_ft
__device__ __forceinline__ void edge_layer(int l, int q, int f, int n, int i,
       const float* __restrict__ projSrc,
       const float* __restrict__ conv_Wf, const float* __restrict__ conv_bf,
       const float* __restrict__ conv_Ws, const float* __restrict__ conv_bs,
       const int* s_nj, const float* s_nd, const float* s_nw,
       float (*s_p)[FF], float (*sm)[FF], float* s_ft)
{
  const float* Wf2 = conv_Wf + l*3*FF*FF + 2*FF*FF;
  const float* Ws2 = conv_Ws + l*3*FF*FF + 2*FF*FF;
  const float gi  = s_p[0][f];          // own projections stay in LDS
  const float si  = s_p[2][f];
  const float bff = conv_bf[l*FF+f];
  const float bsf = conv_bs[l*FF+f];
  float msg = 0.f;
  for (int e = q; e < n; e += 4) {
    const int   jg   = s_nj[e];
    const float dist = s_nd[e];
    const float w    = s_nw[e];
    const float gj   = ld_agent(&projSrc[(jg*4+1)*FF+f]);  // LLC-coherent read
    const float sj   = ld_agent(&projSrc[(jg*4+3)*FF+f]);
    float ge, se;
    band_dot(dist, Wf2, Ws2, f, ge, se);
    msg += sigmoidf(gi + gj + ge + bff) * softplusf(si + sj + se + bsf) * w;
  }
  sm[q][f] = msg;
  __syncthreads();
  if (threadIdx.x < FF) {
    float v = softplusf(s_ft[f] + sm[0][f] + sm[1][f] + sm[2][f] + sm[3][f]);
    s_ft[f] = v;
  }
  __syncthreads();
}

// ============ single fused kernel: 3 sigma blocks + 384 atom blocks ============
// Co-residency: 387 blocks x 512 thr; launch_bounds(512,4) -> <=128 VGPR ->
// >=2 blocks/CU -> 512 resident slots >= 387. Per-batch spins cannot deadlock.
__global__ void __launch_bounds__(512, 4)
k_fused(const float* __restrict__ pos, const float* __restrict__ cell,
        const float* __restrict__ emb,
        const float* __restrict__ conv_Wf, const float* __restrict__ conv_bf,
        const float* __restrict__ conv_Ws, const float* __restrict__ conv_bs,
        const float* __restrict__ fc_W,  const float* __restrict__ fc_b,
        const float* __restrict__ W_out, const float* __restrict__ b_out,
        const int* __restrict__ z, float* __restrict__ out)
{
  const int tid = threadIdx.x;
  const int q = tid >> 7, f = tid & 127;

  if (blockIdx.x < 3) {
    // ---- spectral-norm power iteration (5 iters, eps=1e-12), W read from L2 ----
    // (no 66KB LDS staging: keeps fused-kernel LDS small for residency)
    const int m = blockIdx.x;
    const float* W = fc_W + m*FF*FF;
    __shared__ float s_u[FF], s_v[FF], s_red2[FF];
    __shared__ float s_part2[4][FF];
    if (tid < FF) s_u[tid] = 0.08838834764831845f;      // 1/sqrt(128)
    __syncthreads();
    for (int it = 0; it < 5; it++) {
      { float p = 0.f;                                  // v = W u (k-split)
        #pragma unroll
        for (int k = q*32; k < q*32+32; k++) p += W[f*FF+k]*s_u[k];
        s_part2[q][f] = p; }
      __syncthreads();
      if (tid < FF) { float s = s_part2[0][f]+s_part2[1][f]+s_part2[2][f]+s_part2[3][f];
                      s_v[f] = s; s_red2[f] = s*s; }
      __syncthreads();
      for (int st=64; st>0; st>>=1){ if (tid<st) s_red2[tid]+=s_red2[tid+st]; __syncthreads(); }
      float nv = sqrtf(s_red2[0]) + 1e-12f;
      __syncthreads();
      if (tid < FF) s_v[f] /= nv;
      __syncthreads();
      { float p = 0.f;                                  // u = W^T v (r-split, coalesced)
        #pragma unroll
        for (int r = q*32; r < q*32+32; r++) p += W[r*FF+f]*s_v[r];
        s_part2[q][f] = p; }
      __syncthreads();
      if (tid < FF) { float s = s_part2[0][f]+s_part2[1][f]+s_part2[2][f]+s_part2[3][f];
                      s_u[f] = s; s_red2[f] = s*s; }
      __syncthreads();
      for (int st=64; st>0; st>>=1){ if (tid<st) s_red2[tid]+=s_red2[tid+st]; __syncthreads(); }
      float nu = sqrtf(s_red2[0]) + 1e-12f;
      __syncthreads();
      if (tid < FF) s_u[f] /= nu;
      __syncthreads();
    }
    { float p = 0.f;                                    // sigma = v . (W u)
      #pragma unroll
      for (int k = q*32; k < q*32+32; k++) p += W[f*FF+k]*s_u[k];
      s_part2[q][f] = p; }
    __syncthreads();
    if (tid < FF) s_red2[f] = s_v[f]*(s_part2[0][f]+s_part2[1][f]+s_part2[2][f]+s_part2[3][f]);
    __syncthreads();
    for (int st=64; st>0; st>>=1){ if (tid<st) s_red2[tid]+=s_red2[tid+st]; __syncthreads(); }
    if (tid == 0) {
      st_agent(&g_sigma[m], s_red2[0]);
      asm volatile("s_waitcnt vmcnt(0)" ::: "memory");
      __hip_atomic_fetch_add(&g_sigdone, 1, __ATOMIC_RELEASE, __HIP_MEMORY_SCOPE_AGENT);
    }
    return;
  }

  // ---------------- atom blocks: whole pipeline for one atom ----------------
  const int i = (int)blockIdx.x - 3;
  const int b = i / NN;

  __shared__ float s_ft[FF];          // running feat (residual state)
  __shared__ float s_cell[9];
  __shared__ float s_rb;
  __shared__ int   s_cnt;
  __shared__ int   s_nj[MAXNBR];      // neighbor list lives in LDS now
  __shared__ float s_nd[MAXNBR];
  __shared__ float s_nw[MAXNBR];
  __shared__ float s_p[4][FF];        // own {gi,gj,si,sj} projections
  __shared__ float sm[4][FF];
  __shared__ int   s_last;
  __shared__ float s_hh[FF], s_tmp[FF], s_red[FF];   // FC tail (finisher only)

  // ---- feat0 + cell ----
  if (tid < FF) {
    int zi = z[i]; if (zi < 1) zi = 1; if (zi > 100) zi = 100;
    s_ft[tid] = tanhf(emb[(zi-1)*FF+tid]);
  }
  if (tid >= 256 && tid < 265) s_cell[tid-256] = cell[b*9 + tid - 256];
  if (tid == 500) s_cnt = 0;
  __syncthreads();
  if (tid == 0) {
    const float* c = s_cell;
    float cx = c[4]*c[8] - c[5]*c[7];
    float cy = c[5]*c[6] - c[3]*c[8];
    float cz = c[3]*c[7] - c[4]*c[6];
    float vol = c[0]*cx + c[1]*cy + c[2]*cz;
    s_rb = cbrtf(fabsf(vol)/(float)NN);               // RADIUS_RATE = 1
  }
  __syncthreads();
  // ---- neighbor search (LDS lists) ----
  {
    const float rb = s_rb, rb2 = rb*rb;
    const float pix = pos[i*3+0], piy = pos[i*3+1], piz = pos[i*3+2];
    const float PI = 3.14159265358979323846f;
    for (int cand = tid; cand < NN*CC; cand += 512) {
      int j = cand / CC, c = cand - j*CC;
      float gx = (float)(c/9) - 1.0f;
      float gy = (float)((c/3)%3) - 1.0f;
      float gz = (float)(c%3) - 1.0f;
      float ox = gx*s_cell[0] + gy*s_cell[3] + gz*s_cell[6];
      float oy = gx*s_cell[1] + gy*s_cell[4] + gz*s_cell[7];
      float oz = gx*s_cell[2] + gy*s_cell[5] + gz*s_cell[8];
      int jg = b*NN + j;
      float dx = pix - (pos[jg*3+0] + ox);
      float dy = piy - (pos[jg*3+1] + oy);
      float dz = piz - (pos[jg*3+2] + oz);
      float d2 = dx*dx + dy*dy + dz*dz;
      if (d2 <= rb2 && d2 > 1e-4f) {
        float dist = sqrtf(fmaxf(d2, 1e-12f));
        float w = cosf(dist*PI/rb) + 1.0f;
        int slot = atomicAdd(&s_cnt, 1);              // block-local
        if (slot < MAXNBR) { s_nj[slot] = jg; s_nd[slot] = dist; s_nw[slot] = w; }
      }
    }
  }
  __syncthreads();
  const int n = (s_cnt > MAXNBR) ? MAXNBR : s_cnt;

  // ---- P0 ----
  { float s0 = gemv_q(conv_Wf, conv_Ws, s_ft, q, f);
    s_p[q][f] = s0;
    st_agent(&g_projA[(i*4+q)*FF+f], s0); }
  publish(&g_cnt4[0*NB+b]);
  wait_ge(&g_cnt4[0*NB+b], NN);

  // ---- layer 0 edges + P1 ----
  edge_layer(0, q, f, n, i, g_projA, conv_Wf, conv_bf, conv_Ws, conv_bs,
             s_nj, s_nd, s_nw, s_p, sm, s_ft);
  { float s1 = gemv_q(conv_Wf + 3*FF*FF, conv_Ws + 3*FF*FF, s_ft, q, f);
    s_p[q][f] = s1;
    st_agent(&g_projB[(i*4+q)*FF+f], s1); }
  publish(&g_cnt4[1*NB+b]);
  wait_ge(&g_cnt4[1*NB+b], NN);

  // ---- layer 1 edges + P2 (overwrites P0; all P0 readers have passed c1) ----
  edge_layer(1, q, f, n, i, g_projB, conv_Wf, conv_bf, conv_Ws, conv_bs,
             s_nj, s_nd, s_nw, s_p, sm, s_ft);
  { float s2 = gemv_q(conv_Wf + 2*3*FF*FF, conv_Ws + 2*3*FF*FF, s_ft, q, f);
    s_p[q][f] = s2;
    st_agent(&g_projA[(i*4+q)*FF+f], s2); }
  publish(&g_cnt4[2*NB+b]);
  wait_ge(&g_cnt4[2*NB+b], NN);

  // ---- layer 2 edges + final feat ----
  edge_layer(2, q, f, n, i, g_projA, conv_Wf, conv_bf, conv_Ws, conv_bs,
             s_nj, s_nd, s_nw, s_p, sm, s_ft);
  if (tid < FF) st_agent(&g_feat[i*FF+f], s_ft[f]);
  asm volatile("s_waitcnt vmcnt(0)" ::: "memory");
  __syncthreads();
  if (tid == 0)
    s_last = __hip_atomic_fetch_add(&g_cnt4[3*NB+b], 1, __ATOMIC_ACQ_REL,
                                    __HIP_MEMORY_SCOPE_AGENT);
  __syncthreads();
  if (s_last != NN-1) return;                  // not the last block of this batch

  // ---------- unique last block of batch b: mean + FC chain + head ----------
  if (tid == 0) {                              // sigma must be published
    int guard = 0;
    while (__hip_atomic_load(&g_sigdone, __ATOMIC_ACQUIRE, __HIP_MEMORY_SCOPE_AGENT) < 3) {
      __builtin_amdgcn_s_sleep(2);
      if (++guard > (1<<20)) break;
    }
  }
  __syncthreads();
  if (tid < FF) {
    float s0 = 0.f;
    for (int a = 0; a < NN; a++) s0 += ld_agent(&g_feat[(b*NN+a)*FF+tid]);
    s_hh[tid] = s0/(float)NN;
  }
  __syncthreads();
  for (int l = 0; l < 3; l++) {
    { float p = 0.f;
      #pragma unroll
      for (int k = q*32; k < q*32+32; k++) p += s_hh[k]*fc_W[l*FF*FF + k*FF + f];
      sm[q][f] = p; }
    __syncthreads();
    if (tid < FF) {
      float s = sm[0][tid]+sm[1][tid]+sm[2][tid]+sm[3][tid];
      s_tmp[tid] = softplusf(s/ld_agent(&g_sigma[l]) + fc_b[l*FF+tid]);
    }
    __syncthreads();
    if (tid < FF) s_hh[tid] = s_tmp[tid];
    __syncthreads();
  }
  if (tid < FF) s_red[tid] = s_hh[tid]*W_out[tid];
  __syncthreads();
  if (tid < 64) {
    float t = s_red[tid] + s_red[tid+64];
    #pragma unroll
    for (int off = 32; off > 0; off >>= 1) t += __shfl_xor(t, off);
    if (tid == 0) {
      out[b] = t + b_out[0];
      // reset all per-batch counters for the next graph replay
      __hip_atomic_store(&g_cnt4[0*NB+b], 0, __ATOMIC_RELAXED, __HIP_MEMORY_SCOPE_AGENT);
      __hip_atomic_store(&g_cnt4[1*NB+b], 0, __ATOMIC_RELAXED, __HIP_MEMORY_SCOPE_AGENT);
      __hip_atomic_store(&g_cnt4[2*NB+b], 0, __ATOMIC_RELAXED, __HIP_MEMORY_SCOPE_AGENT);
      __hip_atomic_store(&g_cnt4[3*NB+b], 0, __ATOMIC_RELAXED, __HIP_MEMORY_SCOPE_AGENT);
      int d = __hip_atomic_fetch_add(&g_batchdone, 1, __ATOMIC_ACQ_REL,
                                     __HIP_MEMORY_SCOPE_AGENT);
      if (d == NB-1) {                         // globally last finisher
        __hip_atomic_store(&g_batchdone, 0, __ATOMIC_RELAXED, __HIP_MEMORY_SCOPE_AGENT);
        __hip_atomic_store(&g_sigdone,   0, __ATOMIC_RELAXED, __HIP_MEMORY_SCOPE_AGENT);
      }
    }
  }
}

extern "C" void kernel_launch(void* const* d_in, const int* in_sizes, int n_in,
                              void* d_out, int out_size, void* d_ws, size_t ws_size,
                              hipStream_t stream) {
  const float* pos     = (const float*)d_in[0];
  const float* cell    = (const float*)d_in[1];
  const float* emb     = (const float*)d_in[2];
  const float* conv_Wf = (const float*)d_in[3];
  const float* conv_bf = (const float*)d_in[4];
  const float* conv_Ws = (const float*)d_in[5];
  const float* conv_bs = (const float*)d_in[6];
  const float* fc_W    = (const float*)d_in[7];
  const float* fc_b    = (const float*)d_in[8];
  const float* W_out   = (const float*)d_in[9];
  const float* b_out   = (const float*)d_in[10];
  const int*   z       = (const int*)d_in[11];
  // d_in[12] = batch (unused); d_ws unused. All tensors fp32 (validated R3-R14).

  k_fused<<<NA+3, 512, 0, stream>>>(pos, cell, emb, conv_Wf, conv_bf,
                                    conv_Ws, conv_bs, fc_W, fc_b,
                                    W_out, b_out, z, (float*)d_out);
}

// Round 2
// 243.060 us; speedup vs baseline: 1.1266x; 1.1266x over previous
//
#include <hip/hip_runtime.h>
#include <math.h>

#define NB 16
#define NN 24
#define NA 384       /* atoms total */
#define FF 128
#define CC 27
#define MAXNBR 32    /* physically <= 23 possible (image spacing L > 2r) */

// ---- static device scratch (d_ws unused). Counters are zero at load and reset by
// the unique finisher blocks each call -> clean state per graph replay.
__device__ float g_sigma[4];
__device__ float g_projA[NA*4*FF];  // P0, then P2
__device__ float g_projB[NA*4*FF];  // P1
__device__ float g_feat [NA*FF];    // final feats (agent-scope)
__device__ int   g_cnt4 [4*NB];     // per-layer per-batch arrival counters
__device__ int   g_sigdone;         // sigma blocks done (0..3)
__device__ int   g_batchdone;       // finished batches (0..NB)

__device__ __forceinline__ float softplusf(float x){ return fmaxf(x,0.f) + log1pf(expf(-fabsf(x))); }
__device__ __forceinline__ float sigmoidf(float x){ return 1.f/(1.f+expf(-x)); }
// sc-flagged ops: bypass L1/L2, operate at LLC. NEVER paired with acquire/release
// fences in hot paths -- on gfx9 an agent ACQUIRE = whole-L2 buffer_inv (this was
// R1's 207us regression: acquire-per-poll invalidated weight caching device-wide).
__device__ __forceinline__ void st_agent(float* p, float v){
  __hip_atomic_store(p, v, __ATOMIC_RELAXED, __HIP_MEMORY_SCOPE_AGENT);
}
__device__ __forceinline__ float ld_agent(const float* p){
  return __hip_atomic_load(p, __ATOMIC_RELAXED, __HIP_MEMORY_SCOPE_AGENT);
}

// Fixed-trip banded Gaussian dot: 20 fully-unrolled terms covering the +-9*step band.
// Terms outside the true band have gauss < 2e-18 -> invisible in fp32 sums.
__device__ __forceinline__ void band_dot(float dist, const float* __restrict__ Wf2,
                                         const float* __restrict__ Ws2, int f,
                                         float& ge, float& se)
{
  const float step  = 6.0f/127.0f;
  const float coeff = -0.5f/(step*step);
  int kmin = (int)ceilf(dist/step - 9.0f);
  kmin = kmin < 0 ? 0 : (kmin > 108 ? 108 : kmin);
  float g = 0.f, s = 0.f;
  #pragma unroll
  for (int t = 0; t < 20; t++) {
    int k = kmin + t;
    float dd = dist - step*(float)k;
    float a  = expf(coeff*dd*dd);
    g += a * Wf2[k*FF+f];
    s += a * Ws2[k*FF+f];
  }
  ge = g; se = s;
}

// per-quarter GEMV: quarter q computes one of {gi,gj,si,sj} columns
__device__ __forceinline__ float gemv_q(const float* __restrict__ Wf,
                                        const float* __restrict__ Ws,
                                        const float* s_ft, int q, int f)
{
  const float* W = (q==0) ? Wf : (q==1) ? (Wf + FF*FF) : (q==2) ? Ws : (Ws + FF*FF);
  float s = 0.f;
  #pragma unroll 16
  for (int k = 0; k < FF; k++) s += s_ft[k]*W[k*FF+f];
  return s;
}

// publish own stores at LLC, then bump the per-batch arrival counter.
// vmcnt(0) physically completes the sc stores at the LLC before the atomic
// issues; RELEASE adds only a (clean-L2) writeback, never an invalidate.
__device__ __forceinline__ void publish(int* ctr)
{
  asm volatile("s_waitcnt vmcnt(0)" ::: "memory");   // own agent stores at LLC
  __syncthreads();                                    // whole block drained
  if (threadIdx.x == 0)
    __hip_atomic_fetch_add(ctr, 1, __ATOMIC_RELEASE, __HIP_MEMORY_SCOPE_AGENT);
}

// spin (tid 0 only, bounded) with RELAXED polls -- no cache maintenance.
// Data reads after the wait go through ld_agent (LLC-direct), so no acquire
// fence is needed for visibility.
__device__ __forceinline__ void wait_ge(int* ctr, int target)
{
  if (threadIdx.x == 0) {
    int guard = 0;
    while (__hip_atomic_load(ctr, __ATOMIC_RELAXED, __HIP_MEMORY_SCOPE_AGENT) < target) {
      __builtin_amdgcn_s_sleep(2);
      if (++guard > (1<<20)) break;   // fail visibly (absmax) instead of hanging
    }
  }
  __syncthreads();
}

// edge phase of layer l: msg accumulate + residual softplus update of s_ft
__device__ __forceinline__ void edge_layer(int l, int q, int f, int n, int i,
       const float* __restrict__ projSrc,
       const float* __restrict__ conv_Wf, const float* __restrict__ conv_bf,
       const float* __restrict__ conv_Ws, const float* __restrict__ conv_bs,
       const int* s_nj, const float* s_nd, const float* s_nw,
       float (*s_p)[FF], float (*sm)[FF], float* s_ft)
{
  const float* Wf2 = conv_Wf + l*3*FF*FF + 2*FF*FF;
  const float* Ws2 = conv_Ws + l*3*FF*FF + 2*FF*FF;
  const float gi  = s_p[0][f];          // own projections stay in LDS
  const float si  = s_p[2][f];
  const float bff = conv_bf[l*FF+f];
  const float bsf = conv_bs[l*FF+f];
  float msg = 0.f;
  for (int e = q; e < n; e += 4) {
    const int   jg   = s_nj[e];
    const float dist = s_nd[e];
    const float w    = s_nw[e];
    const float gj   = ld_agent(&projSrc[(jg*4+1)*FF+f]);  // LLC-direct read
    const float sj   = ld_agent(&projSrc[(jg*4+3)*FF+f]);
    float ge, se;
    band_dot(dist, Wf2, Ws2, f, ge, se);
    msg += sigmoidf(gi + gj + ge + bff) * softplusf(si + sj + se + bsf) * w;
  }
  sm[q][f] = msg;
  __syncthreads();
  if (threadIdx.x < FF) {
    float v = softplusf(s_ft[f] + sm[0][f] + sm[1][f] + sm[2][f] + sm[3][f]);
    s_ft[f] = v;
  }
  __syncthreads();
}

// ============ single fused kernel: 3 sigma blocks + 384 atom blocks ============
// Co-residency: 387 blocks x 512 thr; launch_bounds(512,4) -> <=128 VGPR ->
// >=2 blocks/CU -> 512 resident slots >= 387. Per-batch spins cannot deadlock.
__global__ void __launch_bounds__(512, 4)
k_fused(const float* __restrict__ pos, const float* __restrict__ cell,
        const float* __restrict__ emb,
        const float* __restrict__ conv_Wf, const float* __restrict__ conv_bf,
        const float* __restrict__ conv_Ws, const float* __restrict__ conv_bs,
        const float* __restrict__ fc_W,  const float* __restrict__ fc_b,
        const float* __restrict__ W_out, const float* __restrict__ b_out,
        const int* __restrict__ z, float* __restrict__ out)
{
  const int tid = threadIdx.x;
  const int q = tid >> 7, f = tid & 127;

  if (blockIdx.x < 3) {
    // ---- spectral-norm power iteration (5 iters, eps=1e-12), W read from L2 ----
    const int m = blockIdx.x;
    const float* W = fc_W + m*FF*FF;
    __shared__ float s_u[FF], s_v[FF], s_red2[FF];
    __shared__ float s_part2[4][FF];
    if (tid < FF) s_u[tid] = 0.08838834764831845f;      // 1/sqrt(128)
    __syncthreads();
    for (int it = 0; it < 5; it++) {
      { float p = 0.f;                                  // v = W u (k-split)
        #pragma unroll
        for (int k = q*32; k < q*32+32; k++) p += W[f*FF+k]*s_u[k];
        s_part2[q][f] = p; }
      __syncthreads();
      if (tid < FF) { float s = s_part2[0][f]+s_part2[1][f]+s_part2[2][f]+s_part2[3][f];
                      s_v[f] = s; s_red2[f] = s*s; }
      __syncthreads();
      for (int st=64; st>0; st>>=1){ if (tid<st) s_red2[tid]+=s_red2[tid+st]; __syncthreads(); }
      float nv = sqrtf(s_red2[0]) + 1e-12f;
      __syncthreads();
      if (tid < FF) s_v[f] /= nv;
      __syncthreads();
      { float p = 0.f;                                  // u = W^T v (r-split, coalesced)
        #pragma unroll
        for (int r = q*32; r < q*32+32; r++) p += W[r*FF+f]*s_v[r];
        s_part2[q][f] = p; }
      __syncthreads();
      if (tid < FF) { float s = s_part2[0][f]+s_part2[1][f]+s_part2[2][f]+s_part2[3][f];
                      s_u[f] = s; s_red2[f] = s*s; }
      __syncthreads();
      for (int st=64; st>0; st>>=1){ if (tid<st) s_red2[tid]+=s_red2[tid+st]; __syncthreads(); }
      float nu = sqrtf(s_red2[0]) + 1e-12f;
      __syncthreads();
      if (tid < FF) s_u[f] /= nu;
      __syncthreads();
    }
    { float p = 0.f;                                    // sigma = v . (W u)
      #pragma unroll
      for (int k = q*32; k < q*32+32; k++) p += W[f*FF+k]*s_u[k];
      s_part2[q][f] = p; }
    __syncthreads();
    if (tid < FF) s_red2[f] = s_v[f]*(s_part2[0][f]+s_part2[1][f]+s_part2[2][f]+s_part2[3][f]);
    __syncthreads();
    for (int st=64; st>0; st>>=1){ if (tid<st) s_red2[tid]+=s_red2[tid+st]; __syncthreads(); }
    if (tid == 0) {
      st_agent(&g_sigma[m], s_red2[0]);
      asm volatile("s_waitcnt vmcnt(0)" ::: "memory");
      __hip_atomic_fetch_add(&g_sigdone, 1, __ATOMIC_RELEASE, __HIP_MEMORY_SCOPE_AGENT);
    }
    return;
  }

  // ---------------- atom blocks: whole pipeline for one atom ----------------
  const int i = (int)blockIdx.x - 3;
  const int b = i / NN;

  __shared__ float s_ft[FF];          // running feat (residual state)
  __shared__ float s_cell[9];
  __shared__ float s_rb;
  __shared__ int   s_cnt;
  __shared__ int   s_nj[MAXNBR];      // neighbor list in LDS
  __shared__ float s_nd[MAXNBR];
  __shared__ float s_nw[MAXNBR];
  __shared__ float s_p[4][FF];        // own {gi,gj,si,sj} projections
  __shared__ float sm[4][FF];
  __shared__ int   s_last;
  __shared__ float s_hh[FF], s_tmp[FF], s_red[FF];   // FC tail (finisher only)

  // ---- feat0 + cell ----
  if (tid < FF) {
    int zi = z[i]; if (zi < 1) zi = 1; if (zi > 100) zi = 100;
    s_ft[tid] = tanhf(emb[(zi-1)*FF+tid]);
  }
  if (tid >= 256 && tid < 265) s_cell[tid-256] = cell[b*9 + tid - 256];
  if (tid == 500) s_cnt = 0;
  __syncthreads();
  if (tid == 0) {
    const float* c = s_cell;
    float cx = c[4]*c[8] - c[5]*c[7];
    float cy = c[5]*c[6] - c[3]*c[8];
    float cz = c[3]*c[7] - c[4]*c[6];
    float vol = c[0]*cx + c[1]*cy + c[2]*cz;
    s_rb = cbrtf(fabsf(vol)/(float)NN);               // RADIUS_RATE = 1
  }
  __syncthreads();
  // ---- neighbor search (LDS lists) ----
  {
    const float rb = s_rb, rb2 = rb*rb;
    const float pix = pos[i*3+0], piy = pos[i*3+1], piz = pos[i*3+2];
    const float PI = 3.14159265358979323846f;
    for (int cand = tid; cand < NN*CC; cand += 512) {
      int j = cand / CC, c = cand - j*CC;
      float gx = (float)(c/9) - 1.0f;
      float gy = (float)((c/3)%3) - 1.0f;
      float gz = (float)(c%3) - 1.0f;
      float ox = gx*s_cell[0] + gy*s_cell[3] + gz*s_cell[6];
      float oy = gx*s_cell[1] + gy*s_cell[4] + gz*s_cell[7];
      float oz = gx*s_cell[2] + gy*s_cell[5] + gz*s_cell[8];
      int jg = b*NN + j;
      float dx = pix - (pos[jg*3+0] + ox);
      float dy = piy - (pos[jg*3+1] + oy);
      float dz = piz - (pos[jg*3+2] + oz);
      float d2 = dx*dx + dy*dy + dz*dz;
      if (d2 <= rb2 && d2 > 1e-4f) {
        float dist = sqrtf(fmaxf(d2, 1e-4f));
        float w = cosf(dist*PI/rb) + 1.0f;
        int slot = atomicAdd(&s_cnt, 1);              // block-local
        if (slot < MAXNBR) { s_nj[slot] = jg; s_nd[slot] = dist; s_nw[slot] = w; }
      }
    }
  }
  __syncthreads();
  const int n = (s_cnt > MAXNBR) ? MAXNBR : s_cnt;

  // ---- P0 ----
  { float s0 = gemv_q(conv_Wf, conv_Ws, s_ft, q, f);
    s_p[q][f] = s0;
    st_agent(&g_projA[(i*4+q)*FF+f], s0); }
  publish(&g_cnt4[0*NB+b]);
  wait_ge(&g_cnt4[0*NB+b], NN);

  // ---- layer 0 edges + P1 ----
  edge_layer(0, q, f, n, i, g_projA, conv_Wf, conv_bf, conv_Ws, conv_bs,
             s_nj, s_nd, s_nw, s_p, sm, s_ft);
  { float s1 = gemv_q(conv_Wf + 3*FF*FF, conv_Ws + 3*FF*FF, s_ft, q, f);
    s_p[q][f] = s1;
    st_agent(&g_projB[(i*4+q)*FF+f], s1); }
  publish(&g_cnt4[1*NB+b]);
  wait_ge(&g_cnt4[1*NB+b], NN);

  // ---- layer 1 edges + P2 (overwrites P0; all P0 readers have passed c1) ----
  edge_layer(1, q, f, n, i, g_projB, conv_Wf, conv_bf, conv_Ws, conv_bs,
             s_nj, s_nd, s_nw, s_p, sm, s_ft);
  { float s2 = gemv_q(conv_Wf + 2*3*FF*FF, conv_Ws + 2*3*FF*FF, s_ft, q, f);
    s_p[q][f] = s2;
    st_agent(&g_projA[(i*4+q)*FF+f], s2); }
  publish(&g_cnt4[2*NB+b]);
  wait_ge(&g_cnt4[2*NB+b], NN);

  // ---- layer 2 edges + final feat ----
  edge_layer(2, q, f, n, i, g_projA, conv_Wf, conv_bf, conv_Ws, conv_bs,
             s_nj, s_nd, s_nw, s_p, sm, s_ft);
  if (tid < FF) st_agent(&g_feat[i*FF+f], s_ft[f]);
  asm volatile("s_waitcnt vmcnt(0)" ::: "memory");
  __syncthreads();
  if (tid == 0)
    s_last = __hip_atomic_fetch_add(&g_cnt4[3*NB+b], 1, __ATOMIC_RELEASE,
                                    __HIP_MEMORY_SCOPE_AGENT);
  __syncthreads();
  if (s_last != NN-1) return;                  // not the last block of this batch

  // ---------- unique last block of batch b: mean + FC chain + head ----------
  if (tid == 0) {                              // sigma must be published
    int guard = 0;
    while (__hip_atomic_load(&g_sigdone, __ATOMIC_RELAXED, __HIP_MEMORY_SCOPE_AGENT) < 3) {
      __builtin_amdgcn_s_sleep(2);
      if (++guard > (1<<20)) break;
    }
  }
  __syncthreads();
  if (tid < FF) {
    float s0 = 0.f;
    for (int a = 0; a < NN; a++) s0 += ld_agent(&g_feat[(b*NN+a)*FF+tid]);
    s_hh[tid] = s0/(float)NN;
  }
  __syncthreads();
  for (int l = 0; l < 3; l++) {
    { float p = 0.f;
      #pragma unroll
      for (int k = q*32; k < q*32+32; k++) p += s_hh[k]*fc_W[l*FF*FF + k*FF + f];
      sm[q][f] = p; }
    __syncthreads();
    if (tid < FF) {
      float s = sm[0][tid]+sm[1][tid]+sm[2][tid]+sm[3][tid];
      s_tmp[tid] = softplusf(s/ld_agent(&g_sigma[l]) + fc_b[l*FF+tid]);
    }
    __syncthreads();
    if (tid < FF) s_hh[tid] = s_tmp[tid];
    __syncthreads();
  }
  if (tid < FF) s_red[tid] = s_hh[tid]*W_out[tid];
  __syncthreads();
  if (tid < 64) {
    float t = s_red[tid] + s_red[tid+64];
    #pragma unroll
    for (int off = 32; off > 0; off >>= 1) t += __shfl_xor(t, off);
    if (tid == 0) {
      out[b] = t + b_out[0];
      // reset all per-batch counters for the next graph replay
      __hip_atomic_store(&g_cnt4[0*NB+b], 0, __ATOMIC_RELAXED, __HIP_MEMORY_SCOPE_AGENT);
      __hip_atomic_store(&g_cnt4[1*NB+b], 0, __ATOMIC_RELAXED, __HIP_MEMORY_SCOPE_AGENT);
      __hip_atomic_store(&g_cnt4[2*NB+b], 0, __ATOMIC_RELAXED, __HIP_MEMORY_SCOPE_AGENT);
      __hip_atomic_store(&g_cnt4[3*NB+b], 0, __ATOMIC_RELAXED, __HIP_MEMORY_SCOPE_AGENT);
      int d = __hip_atomic_fetch_add(&g_batchdone, 1, __ATOMIC_RELEASE,
                                     __HIP_MEMORY_SCOPE_AGENT);
      if (d == NB-1) {                         // globally last finisher
        __hip_atomic_store(&g_batchdone, 0, __ATOMIC_RELAXED, __HIP_MEMORY_SCOPE_AGENT);
        __hip_atomic_store(&g_sigdone,   0, __ATOMIC_RELAXED, __HIP_MEMORY_SCOPE_AGENT);
      }
    }
  }
}

extern "C" void kernel_launch(void* const* d_in, const int* in_sizes, int n_in,
                              void* d_out, int out_size, void* d_ws, size_t ws_size,
                              hipStream_t stream) {
  const float* pos     = (const float*)d_in[0];
  const float* cell    = (const float*)d_in[1];
  const float* emb     = (const float*)d_in[2];
  const float* conv_Wf = (const float*)d_in[3];
  const float* conv_bf = (const float*)d_in[4];
  const float* conv_Ws = (const float*)d_in[5];
  const float* conv_bs = (const float*)d_in[6];
  const float* fc_W    = (const float*)d_in[7];
  const float* fc_b    = (const float*)d_in[8];
  const float* W_out   = (const float*)d_in[9];
  const float* b_out   = (const float*)d_in[10];
  const int*   z       = (const int*)d_in[11];
  // d_in[12] = batch (unused); d_ws unused. All tensors fp32 (validated R3-R14).

  k_fused<<<NA+3, 512, 0, stream>>>(pos, cell, emb, conv_Wf, conv_bf,
                                    conv_Ws, conv_bs, fc_W, fc_b,
                                    W_out, b_out, z, (float*)d_out);
}

// Round 3
// 158.878 us; speedup vs baseline: 1.7236x; 1.5299x over previous
//
#include <hip/hip_runtime.h>
#include <math.h>

#define NB 16
#define NN 24
#define NA 384       /* atoms total */
#define FF 128
#define CC 27
#define MAXNBR 32    /* physically <= 23 possible (image spacing L > 2r) */

// ---- static device scratch (d_ws unused). Counters are zero at load and reset by
// the unique finisher blocks each call -> clean state per graph replay.
// R3: every counter gets its OWN 128-B line. R2 packed all 64 phase-batch counters
// into 2 lines -> ~1 poll/cycle at one LLC slice -> slice saturation -> ~30us
// barriers. Padding + slower polls (s_sleep 16) removes the hotspot.
__device__ float g_sigma[4];
__device__ float g_projA[NA*4*FF];  // P0, then P2
__device__ float g_projB[NA*4*FF];  // P1
__device__ float g_feat [NA*FF];    // final feats (agent-scope)
__device__ __align__(128) int g_ctr[4*NB][32];   // [phase*NB+batch][0], 128B apart
__device__ __align__(128) int g_sigdone[32];     // sigma blocks done (0..3)
__device__ __align__(128) int g_batchdone[32];   // finished batches (0..NB)

__device__ __forceinline__ float softplusf(float x){ return fmaxf(x,0.f) + log1pf(expf(-fabsf(x))); }
__device__ __forceinline__ float sigmoidf(float x){ return 1.f/(1.f+expf(-x)); }
// sc-flagged ops: bypass L1/L2, operate at LLC. No acquire anywhere in hot paths
// (gfx9 agent ACQUIRE = whole-L2 buffer_inv -> R1's 207us regression).
__device__ __forceinline__ void st_agent(float* p, float v){
  __hip_atomic_store(p, v, __ATOMIC_RELAXED, __HIP_MEMORY_SCOPE_AGENT);
}
__device__ __forceinline__ float ld_agent(const float* p){
  return __hip_atomic_load(p, __ATOMIC_RELAXED, __HIP_MEMORY_SCOPE_AGENT);
}

// Fixed-trip banded Gaussian dot: 20 fully-unrolled terms covering the +-9*step band.
// Terms outside the true band have gauss < 2e-18 -> invisible in fp32 sums.
__device__ __forceinline__ void band_dot(float dist, const float* __restrict__ Wf2,
                                         const float* __restrict__ Ws2, int f,
                                         float& ge, float& se)
{
  const float step  = 6.0f/127.0f;
  const float coeff = -0.5f/(step*step);
  int kmin = (int)ceilf(dist/step - 9.0f);
  kmin = kmin < 0 ? 0 : (kmin > 108 ? 108 : kmin);
  float g = 0.f, s = 0.f;
  #pragma unroll
  for (int t = 0; t < 20; t++) {
    int k = kmin + t;
    float dd = dist - step*(float)k;
    float a  = expf(coeff*dd*dd);
    g += a * Wf2[k*FF+f];
    s += a * Ws2[k*FF+f];
  }
  ge = g; se = s;
}

// per-quarter GEMV: quarter q computes one of {gi,gj,si,sj} columns
__device__ __forceinline__ float gemv_q(const float* __restrict__ Wf,
                                        const float* __restrict__ Ws,
                                        const float* s_ft, int q, int f)
{
  const float* W = (q==0) ? Wf : (q==1) ? (Wf + FF*FF) : (q==2) ? Ws : (Ws + FF*FF);
  float s = 0.f;
  #pragma unroll 16
  for (int k = 0; k < FF; k++) s += s_ft[k]*W[k*FF+f];
  return s;
}

// publish own stores at LLC, then bump the per-batch arrival counter.
// vmcnt(0) physically completes the sc stores at the LLC before the atomic
// issues; RELEASE adds only a (clean-L2) writeback, never an invalidate.
__device__ __forceinline__ void publish(int* ctr)
{
  asm volatile("s_waitcnt vmcnt(0)" ::: "memory");   // own agent stores at LLC
  __syncthreads();                                    // whole block drained
  if (threadIdx.x == 0)
    __hip_atomic_fetch_add(ctr, 1, __ATOMIC_RELEASE, __HIP_MEMORY_SCOPE_AGENT);
}

// spin (tid 0 only, bounded) with RELAXED polls on a private 128-B line.
// s_sleep(16) ~= 1024 cyc between polls: detection cost <1us, and the per-line
// poll rate stays far below LLC-slice saturation.
__device__ __forceinline__ void wait_ge(int* ctr, int target)
{
  if (threadIdx.x == 0) {
    int guard = 0;
    while (__hip_atomic_load(ctr, __ATOMIC_RELAXED, __HIP_MEMORY_SCOPE_AGENT) < target) {
      __builtin_amdgcn_s_sleep(16);
      if (++guard > (1<<16)) break;   // fail visibly (absmax) instead of hanging
    }
  }
  __syncthreads();
}

// edge phase of layer l: msg accumulate + residual softplus update of s_ft
__device__ __forceinline__ void edge_layer(int l, int q, int f, int n, int i,
       const float* __restrict__ projSrc,
       const float* __restrict__ conv_Wf, const float* __restrict__ conv_bf,
       const float* __restrict__ conv_Ws, const float* __restrict__ conv_bs,
       const int* s_nj, const float* s_nd, const float* s_nw,
       float (*s_p)[FF], float (*sm)[FF], float* s_ft)
{
  const float* Wf2 = conv_Wf + l*3*FF*FF + 2*FF*FF;
  const float* Ws2 = conv_Ws + l*3*FF*FF + 2*FF*FF;
  const float gi  = s_p[0][f];          // own projections stay in LDS
  const float si  = s_p[2][f];
  const float bff = conv_bf[l*FF+f];
  const float bsf = conv_bs[l*FF+f];
  float msg = 0.f;
  for (int e = q; e < n; e += 4) {
    const int   jg   = s_nj[e];
    const float dist = s_nd[e];
    const float w    = s_nw[e];
    const float gj   = ld_agent(&projSrc[(jg*4+1)*FF+f]);  // LLC-direct read
    const float sj   = ld_agent(&projSrc[(jg*4+3)*FF+f]);
    float ge, se;
    band_dot(dist, Wf2, Ws2, f, ge, se);
    msg += sigmoidf(gi + gj + ge + bff) * softplusf(si + sj + se + bsf) * w;
  }
  sm[q][f] = msg;
  __syncthreads();
  if (threadIdx.x < FF) {
    float v = softplusf(s_ft[f] + sm[0][f] + sm[1][f] + sm[2][f] + sm[3][f]);
    s_ft[f] = v;
  }
  __syncthreads();
}

// ============ single fused kernel: 3 sigma blocks + 384 atom blocks ============
// Co-residency: 387 blocks x 512 thr; launch_bounds(512,4) -> <=128 VGPR ->
// >=2 blocks/CU -> 512 resident slots >= 387. Per-batch spins cannot deadlock.
__global__ void __launch_bounds__(512, 4)
k_fused(const float* __restrict__ pos, const float* __restrict__ cell,
        const float* __restrict__ emb,
        const float* __restrict__ conv_Wf, const float* __restrict__ conv_bf,
        const float* __restrict__ conv_Ws, const float* __restrict__ conv_bs,
        const float* __restrict__ fc_W,  const float* __restrict__ fc_b,
        const float* __restrict__ W_out, const float* __restrict__ b_out,
        const int* __restrict__ z, float* __restrict__ out)
{
  const int tid = threadIdx.x;
  const int q = tid >> 7, f = tid & 127;

  if (blockIdx.x < 3) {
    // ---- spectral-norm power iteration (5 iters, eps=1e-12), W read from L2 ----
    const int m = blockIdx.x;
    const float* W = fc_W + m*FF*FF;
    __shared__ float s_u[FF], s_v[FF], s_red2[FF];
    __shared__ float s_part2[4][FF];
    if (tid < FF) s_u[tid] = 0.08838834764831845f;      // 1/sqrt(128)
    __syncthreads();
    for (int it = 0; it < 5; it++) {
      { float p = 0.f;                                  // v = W u (k-split)
        #pragma unroll
        for (int k = q*32; k < q*32+32; k++) p += W[f*FF+k]*s_u[k];
        s_part2[q][f] = p; }
      __syncthreads();
      if (tid < FF) { float s = s_part2[0][f]+s_part2[1][f]+s_part2[2][f]+s_part2[3][f];
                      s_v[f] = s; s_red2[f] = s*s; }
      __syncthreads();
      for (int st=64; st>0; st>>=1){ if (tid<st) s_red2[tid]+=s_red2[tid+st]; __syncthreads(); }
      float nv = sqrtf(s_red2[0]) + 1e-12f;
      __syncthreads();
      if (tid < FF) s_v[f] /= nv;
      __syncthreads();
      { float p = 0.f;                                  // u = W^T v (r-split, coalesced)
        #pragma unroll
        for (int r = q*32; r < q*32+32; r++) p += W[r*FF+f]*s_v[r];
        s_part2[q][f] = p; }
      __syncthreads();
      if (tid < FF) { float s = s_part2[0][f]+s_part2[1][f]+s_part2[2][f]+s_part2[3][f];
                      s_u[f] = s; s_red2[f] = s*s; }
      __syncthreads();
      for (int st=64; st>0; st>>=1){ if (tid<st) s_red2[tid]+=s_red2[tid+st]; __syncthreads(); }
      float nu = sqrtf(s_red2[0]) + 1e-12f;
      __syncthreads();
      if (tid < FF) s_u[f] /= nu;
      __syncthreads();
    }
    { float p = 0.f;                                    // sigma = v . (W u)
      #pragma unroll
      for (int k = q*32; k < q*32+32; k++) p += W[f*FF+k]*s_u[k];
      s_part2[q][f] = p; }
    __syncthreads();
    if (tid < FF) s_red2[f] = s_v[f]*(s_part2[0][f]+s_part2[1][f]+s_part2[2][f]+s_part2[3][f]);
    __syncthreads();
    for (int st=64; st>0; st>>=1){ if (tid<st) s_red2[tid]+=s_red2[tid+st]; __syncthreads(); }
    if (tid == 0) {
      st_agent(&g_sigma[m], s_red2[0]);
      asm volatile("s_waitcnt vmcnt(0)" ::: "memory");
      __hip_atomic_fetch_add(&g_sigdone[0], 1, __ATOMIC_RELEASE, __HIP_MEMORY_SCOPE_AGENT);
    }
    return;
  }

  // ---------------- atom blocks: whole pipeline for one atom ----------------
  const int i = (int)blockIdx.x - 3;
  const int b = i / NN;

  __shared__ float s_ft[FF];          // running feat (residual state)
  __shared__ float s_cell[9];
  __shared__ float s_rb;
  __shared__ int   s_cnt;
  __shared__ int   s_nj[MAXNBR];      // neighbor list in LDS
  __shared__ float s_nd[MAXNBR];
  __shared__ float s_nw[MAXNBR];
  __shared__ float s_p[4][FF];        // own {gi,gj,si,sj} projections
  __shared__ float sm[4][FF];
  __shared__ int   s_last;
  __shared__ float s_hh[FF], s_tmp[FF], s_red[FF];   // FC tail (finisher only)

  // ---- feat0 + cell ----
  if (tid < FF) {
    int zi = z[i]; if (zi < 1) zi = 1; if (zi > 100) zi = 100;
    s_ft[tid] = tanhf(emb[(zi-1)*FF+tid]);
  }
  if (tid >= 256 && tid < 265) s_cell[tid-256] = cell[b*9 + tid - 256];
  if (tid == 500) s_cnt = 0;
  __syncthreads();
  if (tid == 0) {
    const float* c = s_cell;
    float cx = c[4]*c[8] - c[5]*c[7];
    float cy = c[5]*c[6] - c[3]*c[8];
    float cz = c[3]*c[7] - c[4]*c[6];
    float vol = c[0]*cx + c[1]*cy + c[2]*cz;
    s_rb = cbrtf(fabsf(vol)/(float)NN);               // RADIUS_RATE = 1
  }
  __syncthreads();
  // ---- neighbor search (LDS lists) ----
  {
    const float rb = s_rb, rb2 = rb*rb;
    const float pix = pos[i*3+0], piy = pos[i*3+1], piz = pos[i*3+2];
    const float PI = 3.14159265358979323846f;
    for (int cand = tid; cand < NN*CC; cand += 512) {
      int j = cand / CC, c = cand - j*CC;
      float gx = (float)(c/9) - 1.0f;
      float gy = (float)((c/3)%3) - 1.0f;
      float gz = (float)(c%3) - 1.0f;
      float ox = gx*s_cell[0] + gy*s_cell[3] + gz*s_cell[6];
      float oy = gx*s_cell[1] + gy*s_cell[4] + gz*s_cell[7];
      float oz = gx*s_cell[2] + gy*s_cell[5] + gz*s_cell[8];
      int jg = b*NN + j;
      float dx = pix - (pos[jg*3+0] + ox);
      float dy = piy - (pos[jg*3+1] + oy);
      float dz = piz - (pos[jg*3+2] + oz);
      float d2 = dx*dx + dy*dy + dz*dz;
      if (d2 <= rb2 && d2 > 1e-4f) {
        float dist = sqrtf(fmaxf(d2, 1e-4f));
        float w = cosf(dist*PI/rb) + 1.0f;
        int slot = atomicAdd(&s_cnt, 1);              // block-local
        if (slot < MAXNBR) { s_nj[slot] = jg; s_nd[slot] = dist; s_nw[slot] = w; }
      }
    }
  }
  __syncthreads();
  const int n = (s_cnt > MAXNBR) ? MAXNBR : s_cnt;

  // ---- P0 ----
  { float s0 = gemv_q(conv_Wf, conv_Ws, s_ft, q, f);
    s_p[q][f] = s0;
    st_agent(&g_projA[(i*4+q)*FF+f], s0); }
  publish(&g_ctr[0*NB+b][0]);
  wait_ge(&g_ctr[0*NB+b][0], NN);

  // ---- layer 0 edges + P1 ----
  edge_layer(0, q, f, n, i, g_projA, conv_Wf, conv_bf, conv_Ws, conv_bs,
             s_nj, s_nd, s_nw, s_p, sm, s_ft);
  { float s1 = gemv_q(conv_Wf + 3*FF*FF, conv_Ws + 3*FF*FF, s_ft, q, f);
    s_p[q][f] = s1;
    st_agent(&g_projB[(i*4+q)*FF+f], s1); }
  publish(&g_ctr[1*NB+b][0]);
  wait_ge(&g_ctr[1*NB+b][0], NN);

  // ---- layer 1 edges + P2 (overwrites P0; all P0 readers have passed c1) ----
  edge_layer(1, q, f, n, i, g_projB, conv_Wf, conv_bf, conv_Ws, conv_bs,
             s_nj, s_nd, s_nw, s_p, sm, s_ft);
  { float s2 = gemv_q(conv_Wf + 2*3*FF*FF, conv_Ws + 2*3*FF*FF, s_ft, q, f);
    s_p[q][f] = s2;
    st_agent(&g_projA[(i*4+q)*FF+f], s2); }
  publish(&g_ctr[2*NB+b][0]);
  wait_ge(&g_ctr[2*NB+b][0], NN);

  // ---- layer 2 edges + final feat ----
  edge_layer(2, q, f, n, i, g_projA, conv_Wf, conv_bf, conv_Ws, conv_bs,
             s_nj, s_nd, s_nw, s_p, sm, s_ft);
  if (tid < FF) st_agent(&g_feat[i*FF+f], s_ft[f]);
  asm volatile("s_waitcnt vmcnt(0)" ::: "memory");
  __syncthreads();
  if (tid == 0)
    s_last = __hip_atomic_fetch_add(&g_ctr[3*NB+b][0], 1, __ATOMIC_RELEASE,
                                    __HIP_MEMORY_SCOPE_AGENT);
  __syncthreads();
  if (s_last != NN-1) return;                  // not the last block of this batch

  // ---------- unique last block of batch b: mean + FC chain + head ----------
  if (tid == 0) {                              // sigma must be published
    int guard = 0;
    while (__hip_atomic_load(&g_sigdone[0], __ATOMIC_RELAXED, __HIP_MEMORY_SCOPE_AGENT) < 3) {
      __builtin_amdgcn_s_sleep(16);
      if (++guard > (1<<16)) break;
    }
  }
  __syncthreads();
  if (tid < FF) {
    float s0 = 0.f;
    for (int a = 0; a < NN; a++) s0 += ld_agent(&g_feat[(b*NN+a)*FF+tid]);
    s_hh[tid] = s0/(float)NN;
  }
  __syncthreads();
  for (int l = 0; l < 3; l++) {
    { float p = 0.f;
      #pragma unroll
      for (int k = q*32; k < q*32+32; k++) p += s_hh[k]*fc_W[l*FF*FF + k*FF + f];
      sm[q][f] = p; }
    __syncthreads();
    if (tid < FF) {
      float s = sm[0][tid]+sm[1][tid]+sm[2][tid]+sm[3][tid];
      s_tmp[tid] = softplusf(s/ld_agent(&g_sigma[l]) + fc_b[l*FF+tid]);
    }
    __syncthreads();
    if (tid < FF) s_hh[tid] = s_tmp[tid];
    __syncthreads();
  }
  if (tid < FF) s_red[tid] = s_hh[tid]*W_out[tid];
  __syncthreads();
  if (tid < 64) {
    float t = s_red[tid] + s_red[tid+64];
    #pragma unroll
    for (int off = 32; off > 0; off >>= 1) t += __shfl_xor(t, off);
    if (tid == 0) {
      out[b] = t + b_out[0];
      // reset all per-batch counters for the next graph replay
      __hip_atomic_store(&g_ctr[0*NB+b][0], 0, __ATOMIC_RELAXED, __HIP_MEMORY_SCOPE_AGENT);
      __hip_atomic_store(&g_ctr[1*NB+b][0], 0, __ATOMIC_RELAXED, __HIP_MEMORY_SCOPE_AGENT);
      __hip_atomic_store(&g_ctr[2*NB+b][0], 0, __ATOMIC_RELAXED, __HIP_MEMORY_SCOPE_AGENT);
      __hip_atomic_store(&g_ctr[3*NB+b][0], 0, __ATOMIC_RELAXED, __HIP_MEMORY_SCOPE_AGENT);
      int d = __hip_atomic_fetch_add(&g_batchdone[0], 1, __ATOMIC_RELEASE,
                                     __HIP_MEMORY_SCOPE_AGENT);
      if (d == NB-1) {                         // globally last finisher
        __hip_atomic_store(&g_batchdone[0], 0, __ATOMIC_RELAXED, __HIP_MEMORY_SCOPE_AGENT);
        __hip_atomic_store(&g_sigdone[0],   0, __ATOMIC_RELAXED, __HIP_MEMORY_SCOPE_AGENT);
      }
    }
  }
}

extern "C" void kernel_launch(void* const* d_in, const int* in_sizes, int n_in,
                              void* d_out, int out_size, void* d_ws, size_t ws_size,
                              hipStream_t stream) {
  const float* pos     = (const float*)d_in[0];
  const float* cell    = (const float*)d_in[1];
  const float* emb     = (const float*)d_in[2];
  const float* conv_Wf = (const float*)d_in[3];
  const float* conv_bf = (const float*)d_in[4];
  const float* conv_Ws = (const float*)d_in[5];
  const float* conv_bs = (const float*)d_in[6];
  const float* fc_W    = (const float*)d_in[7];
  const float* fc_b    = (const float*)d_in[8];
  const float* W_out   = (const float*)d_in[9];
  const float* b_out   = (const float*)d_in[10];
  const int*   z       = (const int*)d_in[11];
  // d_in[12] = batch (unused); d_ws unused. All tensors fp32 (validated R3-R14).

  k_fused<<<NA+3, 512, 0, stream>>>(pos, cell, emb, conv_Wf, conv_bf,
                                    conv_Ws, conv_bs, fc_W, fc_b,
                                    W_out, b_out, z, (float*)d_out);
}

// Round 4
// 146.383 us; speedup vs baseline: 1.8707x; 1.0854x over previous
//
#include <hip/hip_runtime.h>
#include <math.h>

#define NB 16
#define NN 24
#define NA 384       /* atoms total */
#define FF 128
#define CC 27
#define MAXNBR 32    /* physically <= 23 possible (image spacing L > 2r) */

// ---- static device scratch (d_ws unused). Counters are zero at load and reset by
// the unique finisher blocks each call -> clean state per graph replay.
// Each counter owns a 128-B line (R3: unpadded counters saturated one LLC slice).
// R4: ALL atomics RELAXED. Agent-scope RELEASE RMW lowers to buffer_wbl2 (full
// L2 writeback walk) on gfx94x/950 -- 1600 of those per replay was the R3 stall.
// Ordering is carried entirely by s_waitcnt vmcnt(0) before each counter bump:
// sc stores are physically complete at the LLC (the agent coherence point)
// before the atomic issues, so no cache op is semantically needed.
__device__ float g_sigma[4];
__device__ float g_projA[NA*4*FF];  // P0, then P2
__device__ float g_projB[NA*4*FF];  // P1
__device__ float g_feat [NA*FF];    // final feats (agent-scope)
__device__ __align__(128) int g_ctr[4*NB][32];   // [phase*NB+batch][0], 128B apart
__device__ __align__(128) int g_sigdone[32];     // sigma blocks done (0..3)
__device__ __align__(128) int g_batchdone[32];   // finished batches (0..NB)

__device__ __forceinline__ float softplusf(float x){ return fmaxf(x,0.f) + log1pf(expf(-fabsf(x))); }
__device__ __forceinline__ float sigmoidf(float x){ return 1.f/(1.f+expf(-x)); }
// sc-flagged ops: bypass L1/L2, operate at LLC. No acquire/release anywhere
// (gfx9 agent ACQUIRE = whole-L2 inv, RELEASE = whole-L2 writeback; both are
// device-wide storms when 384 blocks sync -- R1/R3 regressions).
__device__ __forceinline__ void st_agent(float* p, float v){
  __hip_atomic_store(p, v, __ATOMIC_RELAXED, __HIP_MEMORY_SCOPE_AGENT);
}
__device__ __forceinline__ float ld_agent(const float* p){
  return __hip_atomic_load(p, __ATOMIC_RELAXED, __HIP_MEMORY_SCOPE_AGENT);
}

// Fixed-trip banded Gaussian dot: 20 fully-unrolled terms covering the +-9*step band.
// Terms outside the true band have gauss < 2e-18 -> invisible in fp32 sums.
__device__ __forceinline__ void band_dot(float dist, const float* __restrict__ Wf2,
                                         const float* __restrict__ Ws2, int f,
                                         float& ge, float& se)
{
  const float step  = 6.0f/127.0f;
  const float coeff = -0.5f/(step*step);
  int kmin = (int)ceilf(dist/step - 9.0f);
  kmin = kmin < 0 ? 0 : (kmin > 108 ? 108 : kmin);
  float g = 0.f, s = 0.f;
  #pragma unroll
  for (int t = 0; t < 20; t++) {
    int k = kmin + t;
    float dd = dist - step*(float)k;
    float a  = expf(coeff*dd*dd);
    g += a * Wf2[k*FF+f];
    s += a * Ws2[k*FF+f];
  }
  ge = g; se = s;
}

// per-quarter GEMV: quarter q computes one of {gi,gj,si,sj} columns
__device__ __forceinline__ float gemv_q(const float* __restrict__ Wf,
                                        const float* __restrict__ Ws,
                                        const float* s_ft, int q, int f)
{
  const float* W = (q==0) ? Wf : (q==1) ? (Wf + FF*FF) : (q==2) ? Ws : (Ws + FF*FF);
  float s = 0.f;
  #pragma unroll 16
  for (int k = 0; k < FF; k++) s += s_ft[k]*W[k*FF+f];
  return s;
}

// publish own stores at LLC, then bump the per-batch arrival counter.
// vmcnt(0) physically completes the sc stores at the LLC before the atomic
// issues; the RMW itself is RELAXED (no cache maintenance at all).
__device__ __forceinline__ void publish(int* ctr)
{
  asm volatile("s_waitcnt vmcnt(0)" ::: "memory");   // own agent stores at LLC
  __syncthreads();                                    // whole block drained
  if (threadIdx.x == 0)
    __hip_atomic_fetch_add(ctr, 1, __ATOMIC_RELAXED, __HIP_MEMORY_SCOPE_AGENT);
}

// spin (tid 0 only, bounded) with RELAXED polls on a private 128-B line.
// s_sleep(4) ~= 256 cyc between polls: ~24 pollers/line stays far below
// LLC-slice limits on padded lines; detection quantization ~0.1-0.2us.
__device__ __forceinline__ void wait_ge(int* ctr, int target)
{
  if (threadIdx.x == 0) {
    int guard = 0;
    while (__hip_atomic_load(ctr, __ATOMIC_RELAXED, __HIP_MEMORY_SCOPE_AGENT) < target) {
      __builtin_amdgcn_s_sleep(4);
      if (++guard > (1<<18)) break;   // fail visibly (absmax) instead of hanging
    }
  }
  __syncthreads();
}

// edge phase of layer l: msg accumulate + residual softplus update of s_ft
__device__ __forceinline__ void edge_layer(int l, int q, int f, int n, int i,
       const float* __restrict__ projSrc,
       const float* __restrict__ conv_Wf, const float* __restrict__ conv_bf,
       const float* __restrict__ conv_Ws, const float* __restrict__ conv_bs,
       const int* s_nj, const float* s_nd, const float* s_nw,
       float (*s_p)[FF], float (*sm)[FF], float* s_ft)
{
  const float* Wf2 = conv_Wf + l*3*FF*FF + 2*FF*FF;
  const float* Ws2 = conv_Ws + l*3*FF*FF + 2*FF*FF;
  const float gi  = s_p[0][f];          // own projections stay in LDS
  const float si  = s_p[2][f];
  const float bff = conv_bf[l*FF+f];
  const float bsf = conv_bs[l*FF+f];
  float msg = 0.f;
  for (int e = q; e < n; e += 4) {
    const int   jg   = s_nj[e];
    const float dist = s_nd[e];
    const float w    = s_nw[e];
    const float gj   = ld_agent(&projSrc[(jg*4+1)*FF+f]);  // LLC-direct read
    const float sj   = ld_agent(&projSrc[(jg*4+3)*FF+f]);
    float ge, se;
    band_dot(dist, Wf2, Ws2, f, ge, se);
    msg += sigmoidf(gi + gj + ge + bff) * softplusf(si + sj + se + bsf) * w;
  }
  sm[q][f] = msg;
  __syncthreads();
  if (threadIdx.x < FF) {
    float v = softplusf(s_ft[f] + sm[0][f] + sm[1][f] + sm[2][f] + sm[3][f]);
    s_ft[f] = v;
  }
  __syncthreads();
}

// ============ single fused kernel: 3 sigma blocks + 384 atom blocks ============
// Co-residency: 387 blocks x 512 thr; launch_bounds(512,4) -> <=128 VGPR ->
// >=2 blocks/CU -> 512 resident slots >= 387. Per-batch spins cannot deadlock.
__global__ void __launch_bounds__(512, 4)
k_fused(const float* __restrict__ pos, const float* __restrict__ cell,
        const float* __restrict__ emb,
        const float* __restrict__ conv_Wf, const float* __restrict__ conv_bf,
        const float* __restrict__ conv_Ws, const float* __restrict__ conv_bs,
        const float* __restrict__ fc_W,  const float* __restrict__ fc_b,
        const float* __restrict__ W_out, const float* __restrict__ b_out,
        const int* __restrict__ z, float* __restrict__ out)
{
  const int tid = threadIdx.x;
  const int q = tid >> 7, f = tid & 127;

  if (blockIdx.x < 3) {
    // ---- spectral-norm power iteration (5 iters, eps=1e-12), W read from L2 ----
    const int m = blockIdx.x;
    const float* W = fc_W + m*FF*FF;
    __shared__ float s_u[FF], s_v[FF], s_red2[FF];
    __shared__ float s_part2[4][FF];
    if (tid < FF) s_u[tid] = 0.08838834764831845f;      // 1/sqrt(128)
    __syncthreads();
    for (int it = 0; it < 5; it++) {
      { float p = 0.f;                                  // v = W u (k-split)
        #pragma unroll
        for (int k = q*32; k < q*32+32; k++) p += W[f*FF+k]*s_u[k];
        s_part2[q][f] = p; }
      __syncthreads();
      if (tid < FF) { float s = s_part2[0][f]+s_part2[1][f]+s_part2[2][f]+s_part2[3][f];
                      s_v[f] = s; s_red2[f] = s*s; }
      __syncthreads();
      for (int st=64; st>0; st>>=1){ if (tid<st) s_red2[tid]+=s_red2[tid+st]; __syncthreads(); }
      float nv = sqrtf(s_red2[0]) + 1e-12f;
      __syncthreads();
      if (tid < FF) s_v[f] /= nv;
      __syncthreads();
      { float p = 0.f;                                  // u = W^T v (r-split, coalesced)
        #pragma unroll
        for (int r = q*32; r < q*32+32; r++) p += W[r*FF+f]*s_v[r];
        s_part2[q][f] = p; }
      __syncthreads();
      if (tid < FF) { float s = s_part2[0][f]+s_part2[1][f]+s_part2[2][f]+s_part2[3][f];
                      s_u[f] = s; s_red2[f] = s*s; }
      __syncthreads();
      for (int st=64; st>0; st>>=1){ if (tid<st) s_red2[tid]+=s_red2[tid+st]; __syncthreads(); }
      float nu = sqrtf(s_red2[0]) + 1e-12f;
      __syncthreads();
      if (tid < FF) s_u[f] /= nu;
      __syncthreads();
    }
    { float p = 0.f;                                    // sigma = v . (W u)
      #pragma unroll
      for (int k = q*32; k < q*32+32; k++) p += W[f*FF+k]*s_u[k];
      s_part2[q][f] = p; }
    __syncthreads();
    if (tid < FF) s_red2[f] = s_v[f]*(s_part2[0][f]+s_part2[1][f]+s_part2[2][f]+s_part2[3][f]);
    __syncthreads();
    for (int st=64; st>0; st>>=1){ if (tid<st) s_red2[tid]+=s_red2[tid+st]; __syncthreads(); }
    if (tid == 0) {
      st_agent(&g_sigma[m], s_red2[0]);
      asm volatile("s_waitcnt vmcnt(0)" ::: "memory");
      __hip_atomic_fetch_add(&g_sigdone[0], 1, __ATOMIC_RELAXED, __HIP_MEMORY_SCOPE_AGENT);
    }
    return;
  }

  // ---------------- atom blocks: whole pipeline for one atom ----------------
  const int i = (int)blockIdx.x - 3;
  const int b = i / NN;

  __shared__ float s_ft[FF];          // running feat (residual state)
  __shared__ float s_cell[9];
  __shared__ float s_rb;
  __shared__ int   s_cnt;
  __shared__ int   s_nj[MAXNBR];      // neighbor list in LDS
  __shared__ float s_nd[MAXNBR];
  __shared__ float s_nw[MAXNBR];
  __shared__ float s_p[4][FF];        // own {gi,gj,si,sj} projections
  __shared__ float sm[4][FF];
  __shared__ int   s_last;
  __shared__ float s_hh[FF], s_tmp[FF], s_red[FF];   // FC tail (finisher only)

  // ---- feat0 + cell ----
  if (tid < FF) {
    int zi = z[i]; if (zi < 1) zi = 1; if (zi > 100) zi = 100;
    s_ft[tid] = tanhf(emb[(zi-1)*FF+tid]);
  }
  if (tid >= 256 && tid < 265) s_cell[tid-256] = cell[b*9 + tid - 256];
  if (tid == 500) s_cnt = 0;
  __syncthreads();
  if (tid == 0) {
    const float* c = s_cell;
    float cx = c[4]*c[8] - c[5]*c[7];
    float cy = c[5]*c[6] - c[3]*c[8];
    float cz = c[3]*c[7] - c[4]*c[6];
    float vol = c[0]*cx + c[1]*cy + c[2]*cz;
    s_rb = cbrtf(fabsf(vol)/(float)NN);               // RADIUS_RATE = 1
  }
  __syncthreads();
  // ---- neighbor search (LDS lists) ----
  {
    const float rb = s_rb, rb2 = rb*rb;
    const float pix = pos[i*3+0], piy = pos[i*3+1], piz = pos[i*3+2];
    const float PI = 3.14159265358979323846f;
    for (int cand = tid; cand < NN*CC; cand += 512) {
      int j = cand / CC, c = cand - j*CC;
      float gx = (float)(c/9) - 1.0f;
      float gy = (float)((c/3)%3) - 1.0f;
      float gz = (float)(c%3) - 1.0f;
      float ox = gx*s_cell[0] + gy*s_cell[3] + gz*s_cell[6];
      float oy = gx*s_cell[1] + gy*s_cell[4] + gz*s_cell[7];
      float oz = gx*s_cell[2] + gy*s_cell[5] + gz*s_cell[8];
      int jg = b*NN + j;
      float dx = pix - (pos[jg*3+0] + ox);
      float dy = piy - (pos[jg*3+1] + oy);
      float dz = piz - (pos[jg*3+2] + oz);
      float d2 = dx*dx + dy*dy + dz*dz;
      if (d2 <= rb2 && d2 > 1e-4f) {
        float dist = sqrtf(fmaxf(d2, 1e-4f));
        float w = cosf(dist*PI/rb) + 1.0f;
        int slot = atomicAdd(&s_cnt, 1);              // block-local
        if (slot < MAXNBR) { s_nj[slot] = jg; s_nd[slot] = dist; s_nw[slot] = w; }
      }
    }
  }
  __syncthreads();
  const int n = (s_cnt > MAXNBR) ? MAXNBR : s_cnt;

  // ---- P0 ----
  { float s0 = gemv_q(conv_Wf, conv_Ws, s_ft, q, f);
    s_p[q][f] = s0;
    st_agent(&g_projA[(i*4+q)*FF+f], s0); }
  publish(&g_ctr[0*NB+b][0]);
  wait_ge(&g_ctr[0*NB+b][0], NN);

  // ---- layer 0 edges + P1 ----
  edge_layer(0, q, f, n, i, g_projA, conv_Wf, conv_bf, conv_Ws, conv_bs,
             s_nj, s_nd, s_nw, s_p, sm, s_ft);
  { float s1 = gemv_q(conv_Wf + 3*FF*FF, conv_Ws + 3*FF*FF, s_ft, q, f);
    s_p[q][f] = s1;
    st_agent(&g_projB[(i*4+q)*FF+f], s1); }
  publish(&g_ctr[1*NB+b][0]);
  wait_ge(&g_ctr[1*NB+b][0], NN);

  // ---- layer 1 edges + P2 (overwrites P0; all P0 readers have passed c1) ----
  edge_layer(1, q, f, n, i, g_projB, conv_Wf, conv_bf, conv_Ws, conv_bs,
             s_nj, s_nd, s_nw, s_p, sm, s_ft);
  { float s2 = gemv_q(conv_Wf + 2*3*FF*FF, conv_Ws + 2*3*FF*FF, s_ft, q, f);
    s_p[q][f] = s2;
    st_agent(&g_projA[(i*4+q)*FF+f], s2); }
  publish(&g_ctr[2*NB+b][0]);
  wait_ge(&g_ctr[2*NB+b][0], NN);

  // ---- layer 2 edges + final feat ----
  edge_layer(2, q, f, n, i, g_projA, conv_Wf, conv_bf, conv_Ws, conv_bs,
             s_nj, s_nd, s_nw, s_p, sm, s_ft);
  if (tid < FF) st_agent(&g_feat[i*FF+f], s_ft[f]);
  asm volatile("s_waitcnt vmcnt(0)" ::: "memory");
  __syncthreads();
  if (tid == 0)
    s_last = __hip_atomic_fetch_add(&g_ctr[3*NB+b][0], 1, __ATOMIC_RELAXED,
                                    __HIP_MEMORY_SCOPE_AGENT);
  __syncthreads();
  if (s_last != NN-1) return;                  // not the last block of this batch

  // ---------- unique last block of batch b: mean + FC chain + head ----------
  if (tid == 0) {                              // sigma must be published
    int guard = 0;
    while (__hip_atomic_load(&g_sigdone[0], __ATOMIC_RELAXED, __HIP_MEMORY_SCOPE_AGENT) < 3) {
      __builtin_amdgcn_s_sleep(4);
      if (++guard > (1<<18)) break;
    }
  }
  __syncthreads();
  if (tid < FF) {
    float s0 = 0.f;
    for (int a = 0; a < NN; a++) s0 += ld_agent(&g_feat[(b*NN+a)*FF+tid]);
    s_hh[tid] = s0/(float)NN;
  }
  __syncthreads();
  for (int l = 0; l < 3; l++) {
    { float p = 0.f;
      #pragma unroll
      for (int k = q*32; k < q*32+32; k++) p += s_hh[k]*fc_W[l*FF*FF + k*FF + f];
      sm[q][f] = p; }
    __syncthreads();
    if (tid < FF) {
      float s = sm[0][tid]+sm[1][tid]+sm[2][tid]+sm[3][tid];
      s_tmp[tid] = softplusf(s/ld_agent(&g_sigma[l]) + fc_b[l*FF+tid]);
    }
    __syncthreads();
    if (tid < FF) s_hh[tid] = s_tmp[tid];
    __syncthreads();
  }
  if (tid < FF) s_red[tid] = s_hh[tid]*W_out[tid];
  __syncthreads();
  if (tid < 64) {
    float t = s_red[tid] + s_red[tid+64];
    #pragma unroll
    for (int off = 32; off > 0; off >>= 1) t += __shfl_xor(t, off);
    if (tid == 0) {
      out[b] = t + b_out[0];
      // reset all per-batch counters for the next graph replay
      __hip_atomic_store(&g_ctr[0*NB+b][0], 0, __ATOMIC_RELAXED, __HIP_MEMORY_SCOPE_AGENT);
      __hip_atomic_store(&g_ctr[1*NB+b][0], 0, __ATOMIC_RELAXED, __HIP_MEMORY_SCOPE_AGENT);
      __hip_atomic_store(&g_ctr[2*NB+b][0], 0, __ATOMIC_RELAXED, __HIP_MEMORY_SCOPE_AGENT);
      __hip_atomic_store(&g_ctr[3*NB+b][0], 0, __ATOMIC_RELAXED, __HIP_MEMORY_SCOPE_AGENT);
      int d = __hip_atomic_fetch_add(&g_batchdone[0], 1, __ATOMIC_RELAXED,
                                     __HIP_MEMORY_SCOPE_AGENT);
      if (d == NB-1) {                         // globally last finisher
        __hip_atomic_store(&g_batchdone[0], 0, __ATOMIC_RELAXED, __HIP_MEMORY_SCOPE_AGENT);
        __hip_atomic_store(&g_sigdone[0],   0, __ATOMIC_RELAXED, __HIP_MEMORY_SCOPE_AGENT);
      }
    }
  }
}

extern "C" void kernel_launch(void* const* d_in, const int* in_sizes, int n_in,
                              void* d_out, int out_size, void* d_ws, size_t ws_size,
                              hipStream_t stream) {
  const float* pos     = (const float*)d_in[0];
  const float* cell    = (const float*)d_in[1];
  const float* emb     = (const float*)d_in[2];
  const float* conv_Wf = (const float*)d_in[3];
  const float* conv_bf = (const float*)d_in[4];
  const float* conv_Ws = (const float*)d_in[5];
  const float* conv_bs = (const float*)d_in[6];
  const float* fc_W    = (const float*)d_in[7];
  const float* fc_b    = (const float*)d_in[8];
  const float* W_out   = (const float*)d_in[9];
  const float* b_out   = (const float*)d_in[10];
  const int*   z       = (const int*)d_in[11];
  // d_in[12] = batch (unused); d_ws unused. All tensors fp32 (validated R3-R14).

  k_fused<<<NA+3, 512, 0, stream>>>(pos, cell, emb, conv_Wf, conv_bf,
                                    conv_Ws, conv_bs, fc_W, fc_b,
                                    W_out, b_out, z, (float*)d_out);
}